// Round 1
// baseline (250.896 us; speedup 1.0000x reference)
//
#include <hip/hip_runtime.h>
#include <hip/hip_bf16.h>
#include <stdint.h>

typedef __attribute__((ext_vector_type(4))) float  floatx4;
typedef __attribute__((ext_vector_type(8))) short  short8;
typedef __attribute__((ext_vector_type(8))) unsigned short ushortx8;
typedef __attribute__((ext_vector_type(4))) unsigned short ushortx4;

#define B_  2
#define T_  2048
#define E_  1024
#define H_  16
#define D_  64
#define C_  128
#define NC_ 16
#define M_  4096   /* B*T */
#define EPS_ 1e-5f

__device__ __forceinline__ unsigned short f2b(float f) {
    union { float f; unsigned int u; } v; v.f = f;
    unsigned int r = v.u + 0x7fffu + ((v.u >> 16) & 1u);
    return (unsigned short)(r >> 16);
}
__device__ __forceinline__ float b2f(unsigned short b) {
    union { unsigned int u; float f; } v; v.u = ((unsigned int)b) << 16;
    return v.f;
}

// ---------------- fp32 -> bf16 convert ----------------
__global__ __launch_bounds__(256) void convert_kernel(const float* __restrict__ src,
                                                      unsigned short* __restrict__ dst, int n) {
    int i = (blockIdx.x * 256 + threadIdx.x) * 4;
    if (i < n) {
        float4 f = *(const float4*)(src + i);
        ushortx4 o;
        o[0] = f2b(f.x); o[1] = f2b(f.y); o[2] = f2b(f.z); o[3] = f2b(f.w);
        *(ushortx4*)(dst + i) = o;
    }
}

// ---------------- QKV projection GEMM: C[4096,3072] = X @ W^T, phi on q,k ----------------
__global__ __launch_bounds__(256) void gemm_qkv(const unsigned short* __restrict__ A,
                                                const unsigned short* __restrict__ Bm,
                                                unsigned short* __restrict__ Cb) {
    const int N = 3 * E_, K = E_;
    __shared__ __align__(16) unsigned short at[128 * 32];
    __shared__ __align__(16) unsigned short bt[128 * 32];
    int tid = threadIdx.x;
    int wave = tid >> 6, lane = tid & 63;
    int wr = wave >> 1, wc = wave & 1;
    int lrow = lane & 15, lk = (lane >> 4) * 8;
    int row0 = blockIdx.y * 128, col0 = blockIdx.x * 128;
    floatx4 acc[4][4];
    for (int i = 0; i < 4; i++) for (int j = 0; j < 4; j++) acc[i][j] = floatx4{0.f, 0.f, 0.f, 0.f};

    int t16  = tid * 16;                   // byte offset within a 4096B pass
    int srow = t16 >> 6;                   // 64B per row (32 bf16)
    int scol = ((t16 & 63) >> 4) * 8;      // element offset of 16B segment

    for (int k0 = 0; k0 < K; k0 += 32) {
        __syncthreads();
        for (int p = 0; p < 2; p++) {
            int r = p * 64 + srow;
            const unsigned short* ga = A  + (size_t)(row0 + r) * K + k0 + scol;
            const unsigned short* gb = Bm + (size_t)(col0 + r) * K + k0 + scol;
            __builtin_amdgcn_global_load_lds((const __attribute__((address_space(1))) unsigned int*)ga,
                (__attribute__((address_space(3))) unsigned int*)(at + p * 2048 + wave * 512), 16, 0, 0);
            __builtin_amdgcn_global_load_lds((const __attribute__((address_space(1))) unsigned int*)gb,
                (__attribute__((address_space(3))) unsigned int*)(bt + p * 2048 + wave * 512), 16, 0, 0);
        }
        __syncthreads();
        short8 af[4], bfr[4];
        for (int mi = 0; mi < 4; mi++) af[mi]  = *(const short8*)(at + (wr * 64 + mi * 16 + lrow) * 32 + lk);
        for (int ni = 0; ni < 4; ni++) bfr[ni] = *(const short8*)(bt + (wc * 64 + ni * 16 + lrow) * 32 + lk);
        for (int mi = 0; mi < 4; mi++)
            for (int ni = 0; ni < 4; ni++)
                acc[mi][ni] = __builtin_amdgcn_mfma_f32_16x16x32_bf16(af[mi], bfr[ni], acc[mi][ni], 0, 0, 0);
    }
    int qrow = (lane >> 4) * 4;
    int qcol = lane & 15;
    for (int mi = 0; mi < 4; mi++) for (int ni = 0; ni < 4; ni++) {
        int col = col0 + wc * 64 + ni * 16 + qcol;
        bool isphi = (col < 2 * E_);
        for (int r2 = 0; r2 < 4; r2++) {
            int row = row0 + wr * 64 + mi * 16 + qrow + r2;
            float v = acc[mi][ni][r2];
            if (isphi) v = (v > 0.f) ? (v + 1.f) : __expf(v);
            Cb[(size_t)row * N + col] = f2b(v);
        }
    }
}

// ---------------- Output GEMM: out[4096,1024] = attn @ Wo^T + bo (fp32 out) ----------------
__global__ __launch_bounds__(256) void gemm_out(const unsigned short* __restrict__ A,
                                                const unsigned short* __restrict__ Bm,
                                                const float* __restrict__ bias,
                                                float* __restrict__ Cf) {
    const int N = E_, K = E_;
    __shared__ __align__(16) unsigned short at[128 * 32];
    __shared__ __align__(16) unsigned short bt[128 * 32];
    int tid = threadIdx.x;
    int wave = tid >> 6, lane = tid & 63;
    int wr = wave >> 1, wc = wave & 1;
    int lrow = lane & 15, lk = (lane >> 4) * 8;
    int row0 = blockIdx.y * 128, col0 = blockIdx.x * 128;
    floatx4 acc[4][4];
    for (int i = 0; i < 4; i++) for (int j = 0; j < 4; j++) acc[i][j] = floatx4{0.f, 0.f, 0.f, 0.f};

    int t16  = tid * 16;
    int srow = t16 >> 6;
    int scol = ((t16 & 63) >> 4) * 8;

    for (int k0 = 0; k0 < K; k0 += 32) {
        __syncthreads();
        for (int p = 0; p < 2; p++) {
            int r = p * 64 + srow;
            const unsigned short* ga = A  + (size_t)(row0 + r) * K + k0 + scol;
            const unsigned short* gb = Bm + (size_t)(col0 + r) * K + k0 + scol;
            __builtin_amdgcn_global_load_lds((const __attribute__((address_space(1))) unsigned int*)ga,
                (__attribute__((address_space(3))) unsigned int*)(at + p * 2048 + wave * 512), 16, 0, 0);
            __builtin_amdgcn_global_load_lds((const __attribute__((address_space(1))) unsigned int*)gb,
                (__attribute__((address_space(3))) unsigned int*)(bt + p * 2048 + wave * 512), 16, 0, 0);
        }
        __syncthreads();
        short8 af[4], bfr[4];
        for (int mi = 0; mi < 4; mi++) af[mi]  = *(const short8*)(at + (wr * 64 + mi * 16 + lrow) * 32 + lk);
        for (int ni = 0; ni < 4; ni++) bfr[ni] = *(const short8*)(bt + (wc * 64 + ni * 16 + lrow) * 32 + lk);
        for (int mi = 0; mi < 4; mi++)
            for (int ni = 0; ni < 4; ni++)
                acc[mi][ni] = __builtin_amdgcn_mfma_f32_16x16x32_bf16(af[mi], bfr[ni], acc[mi][ni], 0, 0, 0);
    }
    int qrow = (lane >> 4) * 4;
    int qcol = lane & 15;
    for (int mi = 0; mi < 4; mi++) for (int ni = 0; ni < 4; ni++) {
        int col = col0 + wc * 64 + ni * 16 + qcol;
        float bv = bias[col];
        for (int r2 = 0; r2 < 4; r2++) {
            int row = row0 + wr * 64 + mi * 16 + qrow + r2;
            Cf[(size_t)row * N + col] = acc[mi][ni][r2] + bv;
        }
    }
}

// ---------------- per-chunk S_c = k_c^T v_c (64x64) and z_c = colsum(k_c) ----------------
__global__ __launch_bounds__(256) void chunk_sums(const unsigned short* __restrict__ qkv,
                                                  float* __restrict__ Sc, float* __restrict__ zc) {
    int c = blockIdx.x, h = blockIdx.y, bb = blockIdx.z;
    __shared__ __align__(16) float ksh[64 * 64];
    __shared__ __align__(16) float vsh[64 * 64];
    int tid = threadIdx.x;
    int ta = tid >> 4, tb = tid & 15;
    int a0 = ta * 4, b0 = tb * 4;
    size_t rowb = (size_t)bb * T_ + (size_t)c * C_;
    int kcol = E_ + h * D_, vcol = 2 * E_ + h * D_;
    float Sacc[4][4] = {};
    float zacc[4] = {0.f, 0.f, 0.f, 0.f};
    for (int jt = 0; jt < 2; jt++) {
        __syncthreads();
        for (int s = 0; s < 2; s++) {
            int off = s * 256 + tid;
            int r = off >> 3, seg = (off & 7) * 8;
            size_t g = (rowb + jt * 64 + r) * 3072;
            ushortx8 kv = *(const ushortx8*)(qkv + g + kcol + seg);
            ushortx8 vv = *(const ushortx8*)(qkv + g + vcol + seg);
            for (int e = 0; e < 8; e++) { ksh[r * 64 + seg + e] = b2f(kv[e]); vsh[r * 64 + seg + e] = b2f(vv[e]); }
        }
        __syncthreads();
        for (int j = 0; j < 64; j++) {
            float4 k4 = *(const float4*)(ksh + j * 64 + a0);
            float4 v4 = *(const float4*)(vsh + j * 64 + b0);
            float ka[4] = {k4.x, k4.y, k4.z, k4.w};
            float va[4] = {v4.x, v4.y, v4.z, v4.w};
            for (int r = 0; r < 4; r++) for (int cc = 0; cc < 4; cc++) Sacc[r][cc] += ka[r] * va[cc];
            if (tb == 0) for (int r = 0; r < 4; r++) zacc[r] += ka[r];
        }
    }
    size_t base = ((size_t)(bb * H_ + h) * NC_ + c) * (D_ * D_);
    for (int r = 0; r < 4; r++) {
        float4 o; o.x = Sacc[r][0]; o.y = Sacc[r][1]; o.z = Sacc[r][2]; o.w = Sacc[r][3];
        *(float4*)(Sc + base + (size_t)(a0 + r) * D_ + b0) = o;
    }
    if (tb == 0) {
        size_t zb = ((size_t)(bb * H_ + h) * NC_ + c) * D_;
        for (int r = 0; r < 4; r++) zc[zb + a0 + r] = zacc[r];
    }
}

// ---------------- exclusive prefix scan over chunks ----------------
__global__ __launch_bounds__(256) void scan_kernel(const float* __restrict__ Sc, const float* __restrict__ zc,
                                                   float* __restrict__ Sp, float* __restrict__ zp) {
    int pair = blockIdx.x; int tid = threadIdx.x;
    size_t base = (size_t)pair * NC_ * (D_ * D_);
    float run[16];
    for (int s = 0; s < 16; s++) run[s] = 0.f;
    for (int c = 0; c < NC_; c++) {
        size_t cb = base + (size_t)c * (D_ * D_);
        for (int s = 0; s < 16; s++) {
            size_t idx = cb + s * 256 + tid;
            Sp[idx] = run[s];
            run[s] += Sc[idx];
        }
    }
    if (tid < 64) {
        size_t zbase = (size_t)pair * NC_ * D_;
        float zr = 0.f;
        for (int c = 0; c < NC_; c++) { zp[zbase + c * 64 + tid] = zr; zr += zc[zbase + c * 64 + tid]; }
    }
}

// ---------------- per-chunk attention ----------------
__global__ __launch_bounds__(256) void attn_kernel(const unsigned short* __restrict__ qkv,
                                                   const float* __restrict__ Sp,
                                                   const float* __restrict__ zp,
                                                   unsigned short* __restrict__ attn) {
    int c = blockIdx.x, h = blockIdx.y, bb = blockIdx.z;
    __shared__ __align__(16) unsigned short qs[128 * 68];   // padded stride 68 kills 8-way conflicts
    __shared__ __align__(16) unsigned short ks2[128 * 68];
    __shared__ __align__(16) unsigned short vs[128 * 64];
    __shared__ __align__(16) unsigned short Ss[64 * 64];
    __shared__ __align__(16) unsigned short Ps[128 * 18];
    __shared__ float zs[64];
    int tid = threadIdx.x;
    size_t rowb = (size_t)bb * T_ + (size_t)c * C_;
    int qcol = h * D_, kcol = E_ + h * D_, vcol = 2 * E_ + h * D_;

    for (int s = 0; s < 4; s++) {
        int off = s * 256 + tid;            // 1024 x 8-elem segments
        int r = off >> 3, seg = (off & 7) * 8;
        size_t g = (rowb + r) * 3072;
        ushortx8 q8 = *(const ushortx8*)(qkv + g + qcol + seg);
        ushortx8 k8 = *(const ushortx8*)(qkv + g + kcol + seg);
        ushortx8 v8 = *(const ushortx8*)(qkv + g + vcol + seg);
        for (int e = 0; e < 8; e++) { qs[r * 68 + seg + e] = q8[e]; ks2[r * 68 + seg + e] = k8[e]; }
        *(ushortx8*)(vs + r * 64 + seg) = v8;
    }
    size_t pbase = (size_t)(bb * H_ + h) * NC_ + c;
    const float* Sg = Sp + pbase * (D_ * D_);
    for (int s = 0; s < 16; s++) { int idx = s * 256 + tid; Ss[idx] = f2b(Sg[idx]); }
    if (tid < 64) zs[tid] = zp[pbase * D_ + tid];
    __syncthreads();

    int ty = tid >> 3, tx = tid & 7;
    int i0 = ty * 4, e0 = tx * 8;
    float num[4][8] = {};
    float den[4] = {EPS_, EPS_, EPS_, EPS_};

    // inter-chunk contribution: num += q @ S_prev ; den += q . z_prev
    for (int d0 = 0; d0 < 64; d0 += 4) {
        ushortx4 qv[4];
        for (int r = 0; r < 4; r++) qv[r] = *(const ushortx4*)(qs + (i0 + r) * 68 + d0);
        for (int dd = 0; dd < 4; dd++) {
            int d = d0 + dd;
            float zf = zs[d];
            ushortx8 Sv = *(const ushortx8*)(Ss + d * 64 + e0);
            float qf[4];
            for (int r = 0; r < 4; r++) { qf[r] = b2f(qv[r][dd]); den[r] += qf[r] * zf; }
            for (int e = 0; e < 8; e++) {
                float sf = b2f(Sv[e]);
                for (int r = 0; r < 4; r++) num[r][e] += qf[r] * sf;
            }
        }
    }

    // intra-chunk: stream masked A in 16-column panels through LDS
    int py = tid >> 3, px = tid & 7;
    int ia0 = py * 4, j0 = px * 2;
    for (int jt = 0; jt < 8; jt++) {
        float pacc[4][2] = {};
        for (int d0 = 0; d0 < 64; d0 += 4) {
            ushortx4 qv[4], kv[2];
            for (int r = 0; r < 4; r++)  qv[r]  = *(const ushortx4*)(qs  + (ia0 + r) * 68 + d0);
            for (int jl = 0; jl < 2; jl++) kv[jl] = *(const ushortx4*)(ks2 + (jt * 16 + j0 + jl) * 68 + d0);
            for (int dd = 0; dd < 4; dd++) {
                float kf0 = b2f(kv[0][dd]), kf1 = b2f(kv[1][dd]);
                for (int r = 0; r < 4; r++) {
                    float qf = b2f(qv[r][dd]);
                    pacc[r][0] += qf * kf0;
                    pacc[r][1] += qf * kf1;
                }
            }
        }
        for (int r = 0; r < 4; r++) for (int jl = 0; jl < 2; jl++) {
            int ii = ia0 + r, jj = jt * 16 + j0 + jl;
            float pv = (jj <= ii) ? pacc[r][jl] : 0.f;
            Ps[ii * 18 + j0 + jl] = f2b(pv);
        }
        __syncthreads();
        for (int jl = 0; jl < 16; jl++) {
            int jg = jt * 16 + jl;
            float p[4];
            for (int r = 0; r < 4; r++) p[r] = b2f(Ps[(i0 + r) * 18 + jl]);
            ushortx8 vv = *(const ushortx8*)(vs + jg * 64 + e0);
            for (int r = 0; r < 4; r++) den[r] += p[r];
            for (int e = 0; e < 8; e++) {
                float vf = b2f(vv[e]);
                for (int r = 0; r < 4; r++) num[r][e] += p[r] * vf;
            }
        }
        __syncthreads();
    }

    for (int r = 0; r < 4; r++) {
        float inv = 1.f / den[r];
        ushortx8 o;
        for (int e = 0; e < 8; e++) o[e] = f2b(num[r][e] * inv);
        *(ushortx8*)(attn + (rowb + i0 + r) * E_ + h * D_ + e0) = o;
    }
}

extern "C" void kernel_launch(void* const* d_in, const int* in_sizes, int n_in,
                              void* d_out, int out_size, void* d_ws, size_t ws_size,
                              hipStream_t stream) {
    const float* x  = (const float*)d_in[0];
    const float* Wq = (const float*)d_in[1];
    const float* Wk = (const float*)d_in[2];
    const float* Wv = (const float*)d_in[3];
    const float* Wo = (const float*)d_in[4];
    const float* bo = (const float*)d_in[5];
    float* out = (float*)d_out;

    const size_t MB = 1024 * 1024;
    uint8_t* ws = (uint8_t*)d_ws;
    unsigned short* xb    = (unsigned short*)(ws + 0);        // 8 MB, reused as attn buffer
    unsigned short* wb    = (unsigned short*)(ws + 8 * MB);   // 6 MB (Wq|Wk|Wv bf16)
    unsigned short* wob   = (unsigned short*)(ws + 14 * MB);  // 2 MB
    unsigned short* qkvb  = (unsigned short*)(ws + 16 * MB);  // 24 MB
    float* Sc = (float*)(ws + 40 * MB);                       // 8 MB
    float* zc = (float*)(ws + 48 * MB);                       // 128 KB
    float* Sp = (float*)(ws + 49 * MB);                       // 8 MB
    float* zp = (float*)(ws + 57 * MB);                       // 128 KB
    unsigned short* attnb = xb;

    convert_kernel<<<(M_ * E_) / 1024, 256, 0, stream>>>(x, xb, M_ * E_);
    convert_kernel<<<(E_ * E_) / 1024, 256, 0, stream>>>(Wq, wb,              E_ * E_);
    convert_kernel<<<(E_ * E_) / 1024, 256, 0, stream>>>(Wk, wb + E_ * E_,    E_ * E_);
    convert_kernel<<<(E_ * E_) / 1024, 256, 0, stream>>>(Wv, wb + 2 * E_ * E_, E_ * E_);
    convert_kernel<<<(E_ * E_) / 1024, 256, 0, stream>>>(Wo, wob, E_ * E_);

    gemm_qkv<<<dim3(24, 32), 256, 0, stream>>>(xb, wb, qkvb);
    chunk_sums<<<dim3(NC_, H_, B_), 256, 0, stream>>>(qkvb, Sc, zc);
    scan_kernel<<<B_ * H_, 256, 0, stream>>>(Sc, zc, Sp, zp);
    attn_kernel<<<dim3(NC_, H_, B_), 256, 0, stream>>>(qkvb, Sp, zp, attnb);
    gemm_out<<<dim3(8, 32), 256, 0, stream>>>(attnb, wob, bo, out);
}

// Round 2
// 192.337 us; speedup vs baseline: 1.3045x; 1.3045x over previous
//
#include <hip/hip_runtime.h>
#include <hip/hip_bf16.h>
#include <stdint.h>

typedef __attribute__((ext_vector_type(4))) float  floatx4;
typedef __attribute__((ext_vector_type(8))) short  short8;
typedef __attribute__((ext_vector_type(8))) unsigned short ushortx8;
typedef __attribute__((ext_vector_type(4))) unsigned short ushortx4;

#define B_  2
#define T_  2048
#define E_  1024
#define H_  16
#define D_  64
#define C_  128
#define NC_ 16
#define M_  4096   /* B*T */
#define EPS_ 1e-5f

__device__ __forceinline__ unsigned short f2b(float f) {
    union { float f; unsigned int u; } v; v.f = f;
    unsigned int r = v.u + 0x7fffu + ((v.u >> 16) & 1u);
    return (unsigned short)(r >> 16);
}
__device__ __forceinline__ float b2f(unsigned short b) {
    union { unsigned int u; float f; } v; v.u = ((unsigned int)b) << 16;
    return v.f;
}

// ---------------- fp32 -> bf16 convert ----------------
__global__ __launch_bounds__(256) void convert_kernel(const float* __restrict__ src,
                                                      unsigned short* __restrict__ dst, int n) {
    int i = (blockIdx.x * 256 + threadIdx.x) * 4;
    if (i < n) {
        float4 f = *(const float4*)(src + i);
        ushortx4 o;
        o[0] = f2b(f.x); o[1] = f2b(f.y); o[2] = f2b(f.z); o[3] = f2b(f.w);
        *(ushortx4*)(dst + i) = o;
    }
}

// ---------------- QKV projection GEMM: C[4096,3072] = X @ W^T, phi on q,k ----------------
__global__ __launch_bounds__(256) void gemm_qkv(const unsigned short* __restrict__ A,
                                                const unsigned short* __restrict__ Bm,
                                                unsigned short* __restrict__ Cb) {
    const int N = 3 * E_, K = E_;
    __shared__ __align__(16) unsigned short at[128 * 32];
    __shared__ __align__(16) unsigned short bt[128 * 32];
    int tid = threadIdx.x;
    int wave = tid >> 6, lane = tid & 63;
    int wr = wave >> 1, wc = wave & 1;
    int lrow = lane & 15, lk = (lane >> 4) * 8;
    int row0 = blockIdx.y * 128, col0 = blockIdx.x * 128;
    floatx4 acc[4][4];
    for (int i = 0; i < 4; i++) for (int j = 0; j < 4; j++) acc[i][j] = floatx4{0.f, 0.f, 0.f, 0.f};

    int t16  = tid * 16;                   // byte offset within a 4096B pass
    int srow = t16 >> 6;                   // 64B per row (32 bf16)
    int scol = ((t16 & 63) >> 4) * 8;      // element offset of 16B segment

    for (int k0 = 0; k0 < K; k0 += 32) {
        __syncthreads();
        for (int p = 0; p < 2; p++) {
            int r = p * 64 + srow;
            const unsigned short* ga = A  + (size_t)(row0 + r) * K + k0 + scol;
            const unsigned short* gb = Bm + (size_t)(col0 + r) * K + k0 + scol;
            __builtin_amdgcn_global_load_lds((const __attribute__((address_space(1))) unsigned int*)ga,
                (__attribute__((address_space(3))) unsigned int*)(at + p * 2048 + wave * 512), 16, 0, 0);
            __builtin_amdgcn_global_load_lds((const __attribute__((address_space(1))) unsigned int*)gb,
                (__attribute__((address_space(3))) unsigned int*)(bt + p * 2048 + wave * 512), 16, 0, 0);
        }
        __syncthreads();
        short8 af[4], bfr[4];
        for (int mi = 0; mi < 4; mi++) af[mi]  = *(const short8*)(at + (wr * 64 + mi * 16 + lrow) * 32 + lk);
        for (int ni = 0; ni < 4; ni++) bfr[ni] = *(const short8*)(bt + (wc * 64 + ni * 16 + lrow) * 32 + lk);
        for (int mi = 0; mi < 4; mi++)
            for (int ni = 0; ni < 4; ni++)
                acc[mi][ni] = __builtin_amdgcn_mfma_f32_16x16x32_bf16(af[mi], bfr[ni], acc[mi][ni], 0, 0, 0);
    }
    int qrow = (lane >> 4) * 4;
    int qcol = lane & 15;
    for (int mi = 0; mi < 4; mi++) for (int ni = 0; ni < 4; ni++) {
        int col = col0 + wc * 64 + ni * 16 + qcol;
        bool isphi = (col < 2 * E_);
        for (int r2 = 0; r2 < 4; r2++) {
            int row = row0 + wr * 64 + mi * 16 + qrow + r2;
            float v = acc[mi][ni][r2];
            if (isphi) v = (v > 0.f) ? (v + 1.f) : __expf(v);
            Cb[(size_t)row * N + col] = f2b(v);
        }
    }
}

// ---------------- Output GEMM: out[4096,1024] = attn @ Wo^T + bo (fp32 out) ----------------
__global__ __launch_bounds__(256) void gemm_out(const unsigned short* __restrict__ A,
                                                const unsigned short* __restrict__ Bm,
                                                const float* __restrict__ bias,
                                                float* __restrict__ Cf) {
    const int N = E_, K = E_;
    __shared__ __align__(16) unsigned short at[128 * 32];
    __shared__ __align__(16) unsigned short bt[128 * 32];
    int tid = threadIdx.x;
    int wave = tid >> 6, lane = tid & 63;
    int wr = wave >> 1, wc = wave & 1;
    int lrow = lane & 15, lk = (lane >> 4) * 8;
    int row0 = blockIdx.y * 128, col0 = blockIdx.x * 128;
    floatx4 acc[4][4];
    for (int i = 0; i < 4; i++) for (int j = 0; j < 4; j++) acc[i][j] = floatx4{0.f, 0.f, 0.f, 0.f};

    int t16  = tid * 16;
    int srow = t16 >> 6;
    int scol = ((t16 & 63) >> 4) * 8;

    for (int k0 = 0; k0 < K; k0 += 32) {
        __syncthreads();
        for (int p = 0; p < 2; p++) {
            int r = p * 64 + srow;
            const unsigned short* ga = A  + (size_t)(row0 + r) * K + k0 + scol;
            const unsigned short* gb = Bm + (size_t)(col0 + r) * K + k0 + scol;
            __builtin_amdgcn_global_load_lds((const __attribute__((address_space(1))) unsigned int*)ga,
                (__attribute__((address_space(3))) unsigned int*)(at + p * 2048 + wave * 512), 16, 0, 0);
            __builtin_amdgcn_global_load_lds((const __attribute__((address_space(1))) unsigned int*)gb,
                (__attribute__((address_space(3))) unsigned int*)(bt + p * 2048 + wave * 512), 16, 0, 0);
        }
        __syncthreads();
        short8 af[4], bfr[4];
        for (int mi = 0; mi < 4; mi++) af[mi]  = *(const short8*)(at + (wr * 64 + mi * 16 + lrow) * 32 + lk);
        for (int ni = 0; ni < 4; ni++) bfr[ni] = *(const short8*)(bt + (wc * 64 + ni * 16 + lrow) * 32 + lk);
        for (int mi = 0; mi < 4; mi++)
            for (int ni = 0; ni < 4; ni++)
                acc[mi][ni] = __builtin_amdgcn_mfma_f32_16x16x32_bf16(af[mi], bfr[ni], acc[mi][ni], 0, 0, 0);
    }
    int qrow = (lane >> 4) * 4;
    int qcol = lane & 15;
    for (int mi = 0; mi < 4; mi++) for (int ni = 0; ni < 4; ni++) {
        int col = col0 + wc * 64 + ni * 16 + qcol;
        float bv = bias[col];
        for (int r2 = 0; r2 < 4; r2++) {
            int row = row0 + wr * 64 + mi * 16 + qrow + r2;
            Cf[(size_t)row * N + col] = acc[mi][ni][r2] + bv;
        }
    }
}

// ---------------- per-chunk S_c = k_c^T v_c (64x64) and z_c (MFMA) ----------------
// A = K^T (m=d, k=t), B = V (k=t, n=e); extra n-col 64 = ones -> z_c.
__global__ __launch_bounds__(256) void chunk_sums(const unsigned short* __restrict__ qkv,
                                                  float* __restrict__ Sc, float* __restrict__ zc) {
    int c = blockIdx.x, h = blockIdx.y, bb = blockIdx.z;
    __shared__ __align__(16) unsigned short Kt[64 * 132];   // K^T: [d][t], stride 132 (conflict-free)
    __shared__ __align__(16) unsigned short Vt[80 * 132];   // V^T rows 0..63; row 64 = ones
    int tid = threadIdx.x;
    int lane = tid & 63, w = tid >> 6;
    size_t rowb = (size_t)bb * T_ + (size_t)c * C_;
    int kcol = E_ + h * D_, vcol = 2 * E_ + h * D_;

    for (int s = 0; s < 4; s++) {
        int off = s * 256 + tid;
        int r = off >> 3, seg = (off & 7) * 8;
        size_t g = (rowb + r) * 3072;
        ushortx8 k8 = *(const ushortx8*)(qkv + g + kcol + seg);
        ushortx8 v8 = *(const ushortx8*)(qkv + g + vcol + seg);
        for (int e = 0; e < 8; e++) {
            Kt[(seg + e) * 132 + r] = k8[e];
            Vt[(seg + e) * 132 + r] = v8[e];
        }
    }
    if (tid < 128) Vt[64 * 132 + tid] = 0x3f80;  // ones row (bf16 1.0)
    __syncthreads();

    floatx4 acc[5];
    for (int ni = 0; ni < 5; ni++) acc[ni] = floatx4{0.f, 0.f, 0.f, 0.f};
    int lm = lane & 15, lk = (lane >> 4) * 8;
    for (int k0 = 0; k0 < 128; k0 += 32) {
        short8 af = *(const short8*)(Kt + (w * 16 + lm) * 132 + k0 + lk);
        for (int ni = 0; ni < 5; ni++) {
            short8 bf = *(const short8*)(Vt + (ni * 16 + lm) * 132 + k0 + lk);
            acc[ni] = __builtin_amdgcn_mfma_f32_16x16x32_bf16(af, bf, acc[ni], 0, 0, 0);
        }
    }
    size_t base = ((size_t)(bb * H_ + h) * NC_ + c) * (size_t)(D_ * D_);
    int r0 = w * 16 + (lane >> 4) * 4;
    for (int ni = 0; ni < 4; ni++)
        for (int reg = 0; reg < 4; reg++)
            Sc[base + (size_t)(r0 + reg) * D_ + ni * 16 + lm] = acc[ni][reg];
    if (lm == 0) {
        size_t zb = ((size_t)(bb * H_ + h) * NC_ + c) * D_;
        for (int reg = 0; reg < 4; reg++) zc[zb + r0 + reg] = acc[4][reg];
    }
}

// ---------------- per-chunk attention (MFMA) ----------------
__global__ __launch_bounds__(256) void attn_kernel(const unsigned short* __restrict__ qkv,
                                                   const float* __restrict__ Sc,
                                                   const float* __restrict__ zc,
                                                   unsigned short* __restrict__ attn) {
    int c = blockIdx.x, h = blockIdx.y, bb = blockIdx.z;
    __shared__ __align__(16) unsigned short qs[128 * 68];   // Q row-major, stride 68 (shift 2 dw/row)
    __shared__ __align__(16) unsigned short ks[128 * 68];   // K row-major
    __shared__ __align__(16) unsigned short vt[64 * 132];   // V^T
    __shared__ __align__(16) unsigned short ovl[128 * 36];  // phase A: S_prev^T (stride 68); j-loop: P panel (stride 36)
    __shared__ float zsh[64];
    int tid = threadIdx.x;
    int lane = tid & 63, w = tid >> 6;
    int lm = lane & 15, lq = lane >> 4;
    size_t rowb = (size_t)bb * T_ + (size_t)c * C_;
    int qcol = h * D_, kcol = E_ + h * D_, vcol = 2 * E_ + h * D_;

    // ---- stage q, k (row-major) and v (transposed) ----
    for (int s = 0; s < 4; s++) {
        int off = s * 256 + tid;
        int r = off >> 3, seg = (off & 7) * 8;
        size_t g = (rowb + r) * 3072;
        ushortx8 q8 = *(const ushortx8*)(qkv + g + qcol + seg);
        ushortx8 k8 = *(const ushortx8*)(qkv + g + kcol + seg);
        ushortx8 v8 = *(const ushortx8*)(qkv + g + vcol + seg);
        *(ushortx8*)(qs + r * 68 + seg) = q8;
        *(ushortx8*)(ks + r * 68 + seg) = k8;
        for (int e = 0; e < 8; e++) vt[(seg + e) * 132 + r] = v8[e];
    }
    // ---- S_prev = sum_{j<c} Sc[j]  (store transposed bf16 into ovl, stride 68) ----
    {
        size_t scb = ((size_t)(bb * H_ + h) * NC_) * (size_t)(D_ * D_);
        int p = tid * 16;
        float a[16];
        for (int i = 0; i < 16; i++) a[i] = 0.f;
        for (int j = 0; j < c; j++) {
            const float* Sj = Sc + scb + (size_t)j * (D_ * D_) + p;
            for (int q = 0; q < 16; q += 4) {
                float4 f = *(const float4*)(Sj + q);
                a[q] += f.x; a[q + 1] += f.y; a[q + 2] += f.z; a[q + 3] += f.w;
            }
        }
        for (int i = 0; i < 16; i++) {
            int d = (p + i) >> 6, e = (p + i) & 63;
            ovl[e * 68 + d] = f2b(a[i]);
        }
    }
    // ---- z_prev (fp32) ----
    if (tid < 64) {
        size_t zb = ((size_t)(bb * H_ + h) * NC_) * D_;
        float zr = 0.f;
        for (int j = 0; j < c; j++) zr += zc[zb + (size_t)j * D_ + tid];
        zsh[tid] = zr;
    }
    __syncthreads();

    // ---- phase A: acc = Q @ S_prev  (wave w -> rows [w*32, w*32+32)) ----
    floatx4 acc[2][4];
    for (int mi = 0; mi < 2; mi++) for (int ni = 0; ni < 4; ni++) acc[mi][ni] = floatx4{0.f, 0.f, 0.f, 0.f};
    for (int k0 = 0; k0 < 64; k0 += 32) {
        short8 aq[2];
        for (int mi = 0; mi < 2; mi++)
            aq[mi] = *(const short8*)(qs + (w * 32 + mi * 16 + lm) * 68 + k0 + lq * 8);
        for (int ni = 0; ni < 4; ni++) {
            short8 bs = *(const short8*)(ovl + (ni * 16 + lm) * 68 + k0 + lq * 8);
            for (int mi = 0; mi < 2; mi++)
                acc[mi][ni] = __builtin_amdgcn_mfma_f32_16x16x32_bf16(aq[mi], bs, acc[mi][ni], 0, 0, 0);
        }
    }
    // ---- dsum init: q . z_prev per output row (C-layout rows), fp32 ----
    float dsum[2][4];
    {
        int d0 = lm * 4;
        float4 z4 = *(const float4*)(zsh + d0);
        for (int mi = 0; mi < 2; mi++)
            for (int reg = 0; reg < 4; reg++) {
                int row = w * 32 + mi * 16 + lq * 4 + reg;
                ushortx4 q4 = *(const ushortx4*)(qs + row * 68 + d0);
                dsum[mi][reg] = b2f(q4[0]) * z4.x + b2f(q4[1]) * z4.y + b2f(q4[2]) * z4.z + b2f(q4[3]) * z4.w;
            }
    }
    __syncthreads();  // all waves done reading S_prev^T from ovl before P writes

    // ---- intra-chunk j-loop: wave w only needs j-tiles jt <= w (causality) ----
    for (int jt = 0; jt <= w; jt++) {
        floatx4 pa[2][2];
        for (int mi = 0; mi < 2; mi++) for (int ct = 0; ct < 2; ct++) pa[mi][ct] = floatx4{0.f, 0.f, 0.f, 0.f};
        for (int k0 = 0; k0 < 64; k0 += 32) {
            short8 aq[2];
            for (int mi = 0; mi < 2; mi++)
                aq[mi] = *(const short8*)(qs + (w * 32 + mi * 16 + lm) * 68 + k0 + lq * 8);
            for (int ct = 0; ct < 2; ct++) {
                short8 bk = *(const short8*)(ks + (jt * 32 + ct * 16 + lm) * 68 + k0 + lq * 8);
                for (int mi = 0; mi < 2; mi++)
                    pa[mi][ct] = __builtin_amdgcn_mfma_f32_16x16x32_bf16(aq[mi], bk, pa[mi][ct], 0, 0, 0);
            }
        }
        bool diag = (jt == w);
        for (int mi = 0; mi < 2; mi++)
            for (int ct = 0; ct < 2; ct++)
                for (int reg = 0; reg < 4; reg++) {
                    int il = mi * 16 + lq * 4 + reg;   // row within wave's 32
                    int jl = ct * 16 + lm;             // col within j-tile's 32
                    float v = pa[mi][ct][reg];
                    if (diag && jl > il) v = 0.f;
                    dsum[mi][reg] += v;
                    ovl[(w * 32 + il) * 36 + jl] = f2b(v);
                }
        // PV: P (A-layout from own rows of ovl) x V^T slice, K=32
        short8 ap[2];
        for (int mi = 0; mi < 2; mi++)
            ap[mi] = *(const short8*)(ovl + (w * 32 + mi * 16 + lm) * 36 + lq * 8);
        for (int ni = 0; ni < 4; ni++) {
            short8 bv = *(const short8*)(vt + (ni * 16 + lm) * 132 + jt * 32 + lq * 8);
            for (int mi = 0; mi < 2; mi++)
                acc[mi][ni] = __builtin_amdgcn_mfma_f32_16x16x32_bf16(ap[mi], bv, acc[mi][ni], 0, 0, 0);
        }
    }

    // ---- reduce dsum across the 16-lane col group ----
    for (int off = 1; off < 16; off <<= 1)
        for (int mi = 0; mi < 2; mi++)
            for (int reg = 0; reg < 4; reg++)
                dsum[mi][reg] += __shfl_xor(dsum[mi][reg], off);

    // ---- epilogue: out = num / den ----
    for (int mi = 0; mi < 2; mi++)
        for (int reg = 0; reg < 4; reg++) {
            float inv = 1.f / (dsum[mi][reg] + EPS_);
            int row = w * 32 + mi * 16 + lq * 4 + reg;
            for (int ni = 0; ni < 4; ni++)
                attn[(rowb + row) * E_ + h * D_ + ni * 16 + lm] = f2b(acc[mi][ni][reg] * inv);
        }
}

extern "C" void kernel_launch(void* const* d_in, const int* in_sizes, int n_in,
                              void* d_out, int out_size, void* d_ws, size_t ws_size,
                              hipStream_t stream) {
    const float* x  = (const float*)d_in[0];
    const float* Wq = (const float*)d_in[1];
    const float* Wk = (const float*)d_in[2];
    const float* Wv = (const float*)d_in[3];
    const float* Wo = (const float*)d_in[4];
    const float* bo = (const float*)d_in[5];
    float* out = (float*)d_out;

    const size_t MB = 1024 * 1024;
    uint8_t* ws = (uint8_t*)d_ws;
    unsigned short* xb    = (unsigned short*)(ws + 0);        // 8 MB, reused as attn buffer
    unsigned short* wb    = (unsigned short*)(ws + 8 * MB);   // 6 MB (Wq|Wk|Wv bf16)
    unsigned short* wob   = (unsigned short*)(ws + 14 * MB);  // 2 MB
    unsigned short* qkvb  = (unsigned short*)(ws + 16 * MB);  // 24 MB
    float* Sc = (float*)(ws + 40 * MB);                       // 8 MB
    float* zc = (float*)(ws + 48 * MB);                       // 128 KB
    unsigned short* attnb = xb;

    convert_kernel<<<(M_ * E_) / 1024, 256, 0, stream>>>(x, xb, M_ * E_);
    convert_kernel<<<(E_ * E_) / 1024, 256, 0, stream>>>(Wq, wb,              E_ * E_);
    convert_kernel<<<(E_ * E_) / 1024, 256, 0, stream>>>(Wk, wb + E_ * E_,    E_ * E_);
    convert_kernel<<<(E_ * E_) / 1024, 256, 0, stream>>>(Wv, wb + 2 * E_ * E_, E_ * E_);
    convert_kernel<<<(E_ * E_) / 1024, 256, 0, stream>>>(Wo, wob, E_ * E_);

    gemm_qkv<<<dim3(24, 32), 256, 0, stream>>>(xb, wb, qkvb);
    chunk_sums<<<dim3(NC_, H_, B_), 256, 0, stream>>>(qkvb, Sc, zc);
    attn_kernel<<<dim3(NC_, H_, B_), 256, 0, stream>>>(qkvb, Sc, zc, attnb);
    gemm_out<<<dim3(8, 32), 256, 0, stream>>>(attnb, wob, bo, out);
}